// Round 2
// baseline (4209.346 us; speedup 1.0000x reference)
//
#include <hip/hip_runtime.h>
#include <hip/hip_bf16.h>
#include <stdint.h>

#define DEVI __device__ __forceinline__

typedef __bf16 bf16x8 __attribute__((ext_vector_type(8)));
typedef float f32x4 __attribute__((ext_vector_type(4)));

DEVI float b2f(unsigned short u) { union { unsigned int i; float f; } v; v.i = ((unsigned int)u) << 16; return v.f; }
DEVI unsigned short f2b(float f) {
  union { unsigned int i; float f; } v; v.f = f;
  unsigned int r = (v.i + 0x7fffu + ((v.i >> 16) & 1u)) >> 16;
  return (unsigned short)r;
}
DEVI float blo(unsigned int u) { union { unsigned int i; float f; } v; v.i = u << 16; return v.f; }
DEVI float bhi(unsigned int u) { union { unsigned int i; float f; } v; v.i = u & 0xffff0000u; return v.f; }

#define NEGINF (-__builtin_inff())

// ---------------------------------------------------------------------------
// Runtime dtype detection (device-side, deterministic, graph-safe).
// flags[0]: 1 if float tensors are f32, 0 if bf16.
// flags[1]: 1 if bool masks are byte-packed, 0 if int32.
// Discriminator: in a true bf16 stream the LOW uint16 of each 32-bit word is a
// genuine N(0,1)-ish bf16 (plausible magnitude ~always). In an f32 stream the
// low uint16 is mantissa bits -> random exponent when viewed as bf16 (~14%
// plausible). Masks: int32 bools are strictly {0,1}; packed bytes give words>1.
// ---------------------------------------------------------------------------
__global__ __launch_bounds__(256) void detect_flags(
    const unsigned int* __restrict__ xw, const unsigned int* __restrict__ mw,
    int* __restrict__ flags) {
  const int t = threadIdx.x;
  int cnt = 0, big = 0;
  for (int i = t; i < 4096; i += 256) {
    unsigned int w = xw[i];
    unsigned short lo = (unsigned short)(w & 0xffffu);
    float f = b2f(lo);
    float a = fabsf(f);
    bool plaus = (lo == 0) || (a >= 1e-8f && a <= 256.f);
    cnt += plaus ? 1 : 0;
    big |= (mw[i] > 1u) ? 1 : 0;
  }
  for (int o = 32; o; o >>= 1) { cnt += __shfl_down(cnt, o); big |= __shfl_down(big, o); }
  __shared__ int sc[4], sb[4];
  if ((t & 63) == 0) { sc[t >> 6] = cnt; sb[t >> 6] = big; }
  __syncthreads();
  if (t == 0) {
    flags[0] = (sc[0] + sc[1] + sc[2] + sc[3] < 2048) ? 1 : 0;
    flags[1] = (sb[0] | sb[1] | sb[2] | sb[3]);
  }
}

// Convert a float tensor (f32 or bf16 per flags[0]) into canonical bf16.
// n must be a multiple of 4; launched with n/1024 blocks.
__global__ __launch_bounds__(256) void cvt_bf16(
    const void* __restrict__ src, unsigned short* __restrict__ dst, int n,
    const int* __restrict__ flags) {
  const int f32mode = flags[0];
  int idx = (blockIdx.x * 256 + threadIdx.x) * 4;
  if (idx >= n) return;
  if (f32mode) {
    const float* s = (const float*)src;
    float4 v = *(const float4*)(s + idx);
    dst[idx] = f2b(v.x); dst[idx + 1] = f2b(v.y);
    dst[idx + 2] = f2b(v.z); dst[idx + 3] = f2b(v.w);
  } else {
    *(uint2*)(dst + idx) = *(const uint2*)((const unsigned short*)src + idx);
  }
}

// ---------------------------------------------------------------------------
// Weight transpose (K,N) -> (N,K), bf16
// ---------------------------------------------------------------------------
__global__ __launch_bounds__(256) void transpose_bf16(
    const unsigned short* __restrict__ W, unsigned short* __restrict__ WT, int K, int N) {
  __shared__ __attribute__((aligned(16))) unsigned short tile[32][33];
  int k0 = blockIdx.x * 32, n0 = blockIdx.y * 32;
  int tx = threadIdx.x & 31, ty = threadIdx.x >> 5;
  for (int i = ty; i < 32; i += 8) tile[i][tx] = W[(size_t)(k0 + i) * N + n0 + tx];
  __syncthreads();
  for (int i = ty; i < 32; i += 8) WT[(size_t)(n0 + i) * K + k0 + tx] = tile[tx][i];
}

// ---------------------------------------------------------------------------
// Pack bool masks (2048 rows x 1024) into 64-bit words (2048 x 16).
// flags[1] selects byte-packed vs int32 source.
// ---------------------------------------------------------------------------
__global__ __launch_bounds__(256) void pack_mask(
    const void* __restrict__ m, unsigned long long* __restrict__ bits,
    const int* __restrict__ flags) {
  const int bytemode = flags[1];
  int wv = blockIdx.x * 4 + (threadIdx.x >> 6);
  int lane = threadIdx.x & 63;
  for (int w = 0; w < 16; ++w) {
    int v;
    if (bytemode) v = ((const unsigned char*)m)[(size_t)wv * 1024 + w * 64 + lane];
    else          v = ((const int*)m)[(size_t)wv * 1024 + w * 64 + lane];
    unsigned long long b = __ballot(v != 0);
    if (lane == 0) bits[(size_t)wv * 16 + w] = b;
  }
}

// ---------------------------------------------------------------------------
// LayerNorm (eps 1e-6, no affine) over rows of 1024; writes normalized (lnx)
// and ncond-affine version (xn). Rows 0..2047 star, 2048..4095 hat.
// ---------------------------------------------------------------------------
__global__ __launch_bounds__(256) void ln_affine(
    const unsigned short* __restrict__ xs, const unsigned short* __restrict__ xh,
    const unsigned short* __restrict__ gw, const unsigned short* __restrict__ bw,
    unsigned short* __restrict__ lnx, unsigned short* __restrict__ xn) {
  const int row = blockIdx.x;
  const unsigned short* xp = (row < 2048) ? xs + (size_t)row * 1024 : xh + (size_t)(row - 2048) * 1024;
  const int t = threadIdx.x;
  float v[4]; float s = 0.f, ss = 0.f;
#pragma unroll
  for (int i = 0; i < 4; ++i) { float x = b2f(xp[i * 256 + t]); v[i] = x; s += x; ss += x * x; }
  for (int o = 32; o; o >>= 1) { s += __shfl_down(s, o); ss += __shfl_down(ss, o); }
  __shared__ float red[2][4];
  const int wv = t >> 6, lane = t & 63;
  if (lane == 0) { red[0][wv] = s; red[1][wv] = ss; }
  __syncthreads();
  s = red[0][0] + red[0][1] + red[0][2] + red[0][3];
  ss = red[1][0] + red[1][1] + red[1][2] + red[1][3];
  const float mean = s * (1.f / 1024.f);
  const float var = fmaxf(ss * (1.f / 1024.f) - mean * mean, 0.f);
  const float rstd = rsqrtf(var + 1e-6f);
  const size_t ro = (size_t)row * 1024;
#pragma unroll
  for (int i = 0; i < 4; ++i) {
    int c = i * 256 + t;
    float n = (v[i] - mean) * rstd;
    lnx[ro + c] = f2b(n);
    xn[ro + c] = f2b(n * b2f(gw[c]) + b2f(bw[c]));
  }
}

// ms = lnx * (1 + g[1C]) + g[0C]
__global__ __launch_bounds__(256) void mod_ms(
    const unsigned short* __restrict__ lnx, const unsigned short* __restrict__ gada,
    unsigned short* __restrict__ ms) {
  const size_t idx = ((size_t)blockIdx.x * 256 + threadIdx.x) * 4;
  const int row = (int)(idx >> 10), c = (int)(idx & 1023);
  const size_t gb = (size_t)row * 6144;
#pragma unroll
  for (int i = 0; i < 4; ++i) {
    float sh = b2f(gada[gb + c + i]);
    float sc = b2f(gada[gb + 1024 + c + i]);
    ms[idx + i] = f2b(b2f(lnx[idx + i]) * (1.f + sc) + sh);
  }
}

// m2 = LN(x1) * (1 + g[4C]) + g[3C]   (x1 is f32)
__global__ __launch_bounds__(256) void ln_mod(
    const float* __restrict__ x1, const unsigned short* __restrict__ gada,
    unsigned short* __restrict__ m2) {
  const int row = blockIdx.x;
  const float* xp = x1 + (size_t)row * 1024;
  const int t = threadIdx.x;
  float v[4]; float s = 0.f, ss = 0.f;
#pragma unroll
  for (int i = 0; i < 4; ++i) { float x = xp[i * 256 + t]; v[i] = x; s += x; ss += x * x; }
  for (int o = 32; o; o >>= 1) { s += __shfl_down(s, o); ss += __shfl_down(ss, o); }
  __shared__ float red[2][4];
  const int wv = t >> 6, lane = t & 63;
  if (lane == 0) { red[0][wv] = s; red[1][wv] = ss; }
  __syncthreads();
  s = red[0][0] + red[0][1] + red[0][2] + red[0][3];
  ss = red[1][0] + red[1][1] + red[1][2] + red[1][3];
  const float mean = s * (1.f / 1024.f);
  const float var = fmaxf(ss * (1.f / 1024.f) - mean * mean, 0.f);
  const float rstd = rsqrtf(var + 1e-6f);
  const size_t gb = (size_t)row * 6144;
#pragma unroll
  for (int i = 0; i < 4; ++i) {
    int c = i * 256 + t;
    float n = (v[i] - mean) * rstd;
    float sh = b2f(gada[gb + 3072 + c]);
    float sc = b2f(gada[gb + 4096 + c]);
    m2[(size_t)row * 1024 + c] = f2b(n * (1.f + sc) + sh);
  }
}

// ---------------------------------------------------------------------------
// MFMA GEMM: C[M,N] = A[M,K] @ BT[N,K]^T + bias, fused epilogues.
// 128x128 tile, 4 waves (each 64x64 via 4x4 mfma_f32_16x16x32_bf16).
// ---------------------------------------------------------------------------
enum { EPI_BF16 = 0, EPI_SILU, EPI_GELU, EPI_GATE_XRES, EPI_GATE_OUT };

template <int EPI>
__global__ __launch_bounds__(256) void gemm_bt(
    const unsigned short* __restrict__ A, const unsigned short* __restrict__ BT,
    const unsigned short* __restrict__ bias, void* __restrict__ out,
    int M, int N, int K,
    const unsigned short* __restrict__ gate,  // bf16, row stride 6144 (pre-offset col)
    const void* __restrict__ res0, const void* __restrict__ res1,
    const int* __restrict__ oflags) {
  constexpr int LDK = 40;  // 32 + 8 pad
  __shared__ __attribute__((aligned(16))) unsigned short As[128 * LDK];
  __shared__ __attribute__((aligned(16))) unsigned short Bs[128 * LDK];
  const int m0 = blockIdx.x * 128, n0 = blockIdx.y * 128;
  const int t = threadIdx.x;
  const int wave = t >> 6, lane = t & 63;
  const int wm = (wave >> 1) * 64, wn = (wave & 1) * 64;
  const int l16 = lane & 15, quad = lane >> 4;
  f32x4 acc[4][4] = {};

  const int row_l = t >> 2, col_l = (t & 3) * 8;
  const unsigned short* ga = A + (size_t)(m0 + row_l) * K + col_l;
  const unsigned short* gb = BT + (size_t)(n0 + row_l) * K + col_l;

  for (int k0 = 0; k0 < K; k0 += 32) {
    __syncthreads();
    uint4 a0 = *(const uint4*)(ga + k0);
    uint4 a1 = *(const uint4*)(ga + (size_t)64 * K + k0);
    uint4 b0 = *(const uint4*)(gb + k0);
    uint4 b1 = *(const uint4*)(gb + (size_t)64 * K + k0);
    *(uint4*)&As[row_l * LDK + col_l] = a0;
    *(uint4*)&As[(row_l + 64) * LDK + col_l] = a1;
    *(uint4*)&Bs[row_l * LDK + col_l] = b0;
    *(uint4*)&Bs[(row_l + 64) * LDK + col_l] = b1;
    __syncthreads();
    bf16x8 af[4], bf[4];
#pragma unroll
    for (int i = 0; i < 4; ++i) af[i] = *(const bf16x8*)(const void*)&As[(wm + i * 16 + l16) * LDK + quad * 8];
#pragma unroll
    for (int j = 0; j < 4; ++j) bf[j] = *(const bf16x8*)(const void*)&Bs[(wn + j * 16 + l16) * LDK + quad * 8];
#pragma unroll
    for (int i = 0; i < 4; ++i)
#pragma unroll
      for (int j = 0; j < 4; ++j)
        acc[i][j] = __builtin_amdgcn_mfma_f32_16x16x32_bf16(af[i], bf[j], acc[i][j], 0, 0, 0);
  }

#pragma unroll
  for (int i = 0; i < 4; ++i) {
    const int gm = m0 + wm + i * 16 + quad * 4;
#pragma unroll
    for (int j = 0; j < 4; ++j) {
      const int gn = n0 + wn + j * 16 + l16;
      const float bv = b2f(bias[gn]);
#pragma unroll
      for (int r = 0; r < 4; ++r) {
        const int gmr = gm + r;
        float v = acc[i][j][r] + bv;
        const size_t oi = (size_t)gmr * N + gn;
        if constexpr (EPI == EPI_BF16) {
          ((unsigned short*)out)[oi] = f2b(v);
        } else if constexpr (EPI == EPI_SILU) {
          ((unsigned short*)out)[oi] = f2b(v / (1.f + __expf(-v)));
        } else if constexpr (EPI == EPI_GELU) {
          float u = 0.7978845608028654f * (v + 0.044715f * v * v * v);
          float th = 1.f - 2.f / (__expf(2.f * u) + 1.f);
          ((unsigned short*)out)[oi] = f2b(0.5f * v * (1.f + th));
        } else if constexpr (EPI == EPI_GATE_XRES) {
          float g = b2f(gate[(size_t)gmr * 6144 + gn]);
          const unsigned short* xr = (gmr < 2048) ? (const unsigned short*)res0 : (const unsigned short*)res1;
          float x = b2f(xr[(size_t)(gmr & 2047) * 1024 + gn]);
          ((float*)out)[oi] = x + g * v;
        } else {  // EPI_GATE_OUT
          float g = b2f(gate[(size_t)gmr * 6144 + gn]);
          float x = ((const float*)res0)[oi];
          float r2 = x + g * v;
          if (oflags[0]) ((float*)out)[oi] = r2;
          else ((unsigned short*)out)[oi] = f2b(r2);
        }
      }
    }
  }
}

// ---------------------------------------------------------------------------
// Cross attention: q rows (4096x1024, head h at col h*64), kv (2,256,2048).
// ---------------------------------------------------------------------------
__global__ __launch_bounds__(256) void cross_attn(
    const unsigned short* __restrict__ q, const unsigned short* __restrict__ kv,
    unsigned short* __restrict__ y) {
  __shared__ __attribute__((aligned(16))) unsigned short Ks[256 * 66];
  const int bid = blockIdx.x;
  const int tt = bid & 7, h = (bid >> 3) & 15, b = (bid >> 7) & 1, st = bid >> 8;
  const int t = threadIdx.x, wv = t >> 6, lane = t & 63;
  const unsigned short* kbase = kv + (size_t)b * (256 * 2048) + h * 64;
  const unsigned short* vbase = kbase + 1024;
  for (int it = 0; it < 8; ++it) {
    int ci = it * 256 + t;
    int row = ci >> 3, c8 = (ci & 7) * 8;
    uint4 kd = *(const uint4*)(kbase + (size_t)row * 2048 + c8);
    unsigned int* kp = (unsigned int*)&Ks[row * 66 + c8];
    kp[0] = kd.x; kp[1] = kd.y; kp[2] = kd.z; kp[3] = kd.w;
  }
  __syncthreads();
  const int rbase = st * 2048 + b * 1024 + tt * 128;
  for (int rr = 0; rr < 32; ++rr) {
    const int r = rbase + wv * 32 + rr;
    const unsigned int* qp = (const unsigned int*)(q + (size_t)r * 1024 + h * 64);
    unsigned int qreg[32];
#pragma unroll
    for (int dp = 0; dp < 32; ++dp) qreg[dp] = qp[dp];
    float lg[4];
#pragma unroll
    for (int c = 0; c < 4; ++c) {
      const unsigned int* krow = (const unsigned int*)&Ks[(c * 64 + lane) * 66];
      float acc = 0.f;
#pragma unroll
      for (int dp = 0; dp < 32; ++dp) {
        unsigned int kw = krow[dp], qw = qreg[dp];
        acc += blo(kw) * blo(qw) + bhi(kw) * bhi(qw);
      }
      lg[c] = acc * 0.125f;
    }
    float mx = fmaxf(fmaxf(lg[0], lg[1]), fmaxf(lg[2], lg[3]));
    for (int o = 32; o; o >>= 1) mx = fmaxf(mx, __shfl_xor(mx, o));
    float p[4]; float sum = 0.f;
#pragma unroll
    for (int c = 0; c < 4; ++c) { p[c] = __expf(lg[c] - mx); sum += p[c]; }
    for (int o = 32; o; o >>= 1) sum += __shfl_xor(sum, o);
    float acc2 = 0.f;
#pragma unroll
    for (int c = 0; c < 4; ++c) {
      for (int s = 0; s < 64; ++s) {
        float pvv = __shfl(p[c], s);
        float vv = b2f(vbase[(size_t)(c * 64 + s) * 2048 + lane]);
        acc2 += pvv * vv;
      }
    }
    y[(size_t)r * 1024 + h * 64 + lane] = f2b(acc2 / sum);
  }
}

// ---------------------------------------------------------------------------
// Star self-attention: causal + dep mask, flash-style online softmax.
// ---------------------------------------------------------------------------
__global__ __launch_bounds__(256) void star_attn(
    const unsigned short* __restrict__ qkv, const unsigned long long* __restrict__ depb,
    unsigned short* __restrict__ y) {
  __shared__ __attribute__((aligned(16))) unsigned short Ksm[64 * 66];
  __shared__ __attribute__((aligned(16))) unsigned short Vsm[64 * 66];
  __shared__ __attribute__((aligned(16))) unsigned short qsh[64 * 66];
  const int bid = blockIdx.x;
  const int tt = bid & 15, h = (bid >> 4) & 15, b = bid >> 8;
  const int t = threadIdx.x, wv = t >> 6, lane = t & 63;
  const int t0 = tt * 64;
  const unsigned short* qbase = qkv + (size_t)(b * 1024 + t0) * 3072 + h * 64;
  for (int it = 0; it < 2; ++it) {
    int ci = it * 256 + t; int row = ci >> 3, c8 = (ci & 7) * 8;
    uint4 d = *(const uint4*)(qbase + (size_t)row * 3072 + c8);
    unsigned int* p = (unsigned int*)&qsh[row * 66 + c8];
    p[0] = d.x; p[1] = d.y; p[2] = d.z; p[3] = d.w;
  }
  float m_i[16], l_i[16], y_i[16];
#pragma unroll
  for (int i = 0; i < 16; ++i) { m_i[i] = NEGINF; l_i[i] = 0.f; y_i[i] = 0.f; }
  const unsigned short* kb0 = qkv + (size_t)(b * 1024) * 3072 + 1024 + h * 64;
  const unsigned short* vb0 = qkv + (size_t)(b * 1024) * 3072 + 2048 + h * 64;
  for (int ck = 0; ck <= tt; ++ck) {
    const int s0 = ck * 64;
    __syncthreads();
    for (int it = 0; it < 2; ++it) {
      int ci = it * 256 + t; int row = ci >> 3, c8 = (ci & 7) * 8;
      size_t go = (size_t)(s0 + row) * 3072 + c8;
      uint4 kd = *(const uint4*)(kb0 + go);
      uint4 vd = *(const uint4*)(vb0 + go);
      unsigned int* kp = (unsigned int*)&Ksm[row * 66 + c8];
      kp[0] = kd.x; kp[1] = kd.y; kp[2] = kd.z; kp[3] = kd.w;
      unsigned int* vp = (unsigned int*)&Vsm[row * 66 + c8];
      vp[0] = vd.x; vp[1] = vd.y; vp[2] = vd.z; vp[3] = vd.w;
    }
    __syncthreads();
#pragma unroll
    for (int rr = 0; rr < 16; ++rr) {
      const int tl = wv * 16 + rr;
      const int trow = t0 + tl;
      const unsigned long long dw = depb[((size_t)(b * 1024 + trow)) * 16 + ck];
      if (dw == 0ull) continue;
      const int sg = s0 + lane;
      const bool ok = (sg <= trow) && ((dw >> lane) & 1ull);
      const unsigned int* krow = (const unsigned int*)&Ksm[lane * 66];
      const unsigned int* qrow = (const unsigned int*)&qsh[tl * 66];
      float acc = 0.f;
      for (int dp = 0; dp < 32; ++dp) {
        unsigned int kw = krow[dp], qw = qrow[dp];
        acc += blo(kw) * blo(qw) + bhi(kw) * bhi(qw);
      }
      float lgv = ok ? acc * 0.125f : NEGINF;
      float cm = lgv;
      for (int o = 32; o; o >>= 1) cm = fmaxf(cm, __shfl_xor(cm, o));
      if (cm == NEGINF) continue;
      const float mn = fmaxf(m_i[rr], cm);
      float pv = __expf(lgv - mn);
      float rs = pv;
      for (int o = 32; o; o >>= 1) rs += __shfl_xor(rs, o);
      const float alpha = __expf(m_i[rr] - mn);
      m_i[rr] = mn;
      l_i[rr] = l_i[rr] * alpha + rs;
      float ya = y_i[rr] * alpha;
      for (int s = 0; s < 64; ++s) {
        float ps = __shfl(pv, s);
        ya += ps * b2f(Vsm[s * 66 + lane]);
      }
      y_i[rr] = ya;
    }
  }
#pragma unroll
  for (int rr = 0; rr < 16; ++rr) {
    const int trow = t0 + wv * 16 + rr;
    float ol = l_i[rr];
    y[((size_t)(b * 1024 + trow)) * 1024 + h * 64 + lane] = f2b(ol > 0.f ? y_i[rr] / ol : 0.f);
  }
}

// ---------------------------------------------------------------------------
// Hat self-attention: merged logits, dep mask, PV source selected per key.
// ---------------------------------------------------------------------------
__global__ __launch_bounds__(256) void hat_attn(
    const unsigned short* __restrict__ qkv,
    const unsigned long long* __restrict__ starb, const unsigned long long* __restrict__ hatb,
    const unsigned long long* __restrict__ depb, unsigned short* __restrict__ y) {
  __shared__ __attribute__((aligned(16))) unsigned short Km[2][64 * 66];
  __shared__ __attribute__((aligned(16))) unsigned short Vm[2][64 * 66];
  __shared__ __attribute__((aligned(16))) unsigned short qsh[64 * 66];
  const int bid = blockIdx.x;
  const int tt = bid & 15, h = (bid >> 4) & 15, b = bid >> 8;
  const int t = threadIdx.x, wv = t >> 6, lane = t & 63;
  const int t0 = tt * 64;
  const unsigned short* qbase = qkv + (size_t)(2048 + b * 1024 + t0) * 3072 + h * 64;
  for (int it = 0; it < 2; ++it) {
    int ci = it * 256 + t; int row = ci >> 3, c8 = (ci & 7) * 8;
    uint4 d = *(const uint4*)(qbase + (size_t)row * 3072 + c8);
    unsigned int* p = (unsigned int*)&qsh[row * 66 + c8];
    p[0] = d.x; p[1] = d.y; p[2] = d.z; p[3] = d.w;
  }
  float m_i[16], l_i[16], y_i[16];
#pragma unroll
  for (int i = 0; i < 16; ++i) { m_i[i] = NEGINF; l_i[i] = 0.f; y_i[i] = 0.f; }
  const unsigned short* ksb = qkv + (size_t)(b * 1024) * 3072 + 1024 + h * 64;
  const unsigned short* vsb = qkv + (size_t)(b * 1024) * 3072 + 2048 + h * 64;
  const unsigned short* khb = qkv + (size_t)(2048 + b * 1024) * 3072 + 1024 + h * 64;
  const unsigned short* vhb = qkv + (size_t)(2048 + b * 1024) * 3072 + 2048 + h * 64;
  for (int ck = 0; ck < 16; ++ck) {
    const int s0 = ck * 64;
    __syncthreads();
    for (int it = 0; it < 2; ++it) {
      int ci = it * 256 + t; int row = ci >> 3, c8 = (ci & 7) * 8;
      size_t go = (size_t)(s0 + row) * 3072 + c8;
      uint4 a = *(const uint4*)(ksb + go);
      uint4 bq4 = *(const uint4*)(khb + go);
      uint4 cq = *(const uint4*)(vsb + go);
      uint4 dq = *(const uint4*)(vhb + go);
      unsigned int* p0 = (unsigned int*)&Km[0][row * 66 + c8];
      p0[0] = a.x; p0[1] = a.y; p0[2] = a.z; p0[3] = a.w;
      unsigned int* p1 = (unsigned int*)&Km[1][row * 66 + c8];
      p1[0] = bq4.x; p1[1] = bq4.y; p1[2] = bq4.z; p1[3] = bq4.w;
      unsigned int* p2 = (unsigned int*)&Vm[0][row * 66 + c8];
      p2[0] = cq.x; p2[1] = cq.y; p2[2] = cq.z; p2[3] = cq.w;
      unsigned int* p3 = (unsigned int*)&Vm[1][row * 66 + c8];
      p3[0] = dq.x; p3[1] = dq.y; p3[2] = dq.z; p3[3] = dq.w;
    }
    __syncthreads();
#pragma unroll
    for (int rr = 0; rr < 16; ++rr) {
      const int tl = wv * 16 + rr;
      const int trow = t0 + tl;
      const size_t mrow = ((size_t)(b * 1024 + trow)) * 16 + ck;
      const unsigned long long sw = starb[mrow];
      const unsigned long long hw = hatb[mrow];
      if ((sw | hw) == 0ull) continue;
      const unsigned long long dw = depb[mrow];
      const int ih = (int)((hw >> lane) & 1ull);
      const int is = (int)((sw >> lane) & 1ull);
      const bool ok = ((ih | is) & (int)((dw >> lane) & 1ull)) != 0;
      const unsigned int* krow = (const unsigned int*)&Km[ih][lane * 66];
      const unsigned int* qrow = (const unsigned int*)&qsh[tl * 66];
      float acc = 0.f;
      for (int dp = 0; dp < 32; ++dp) {
        unsigned int kw = krow[dp], qw = qrow[dp];
        acc += blo(kw) * blo(qw) + bhi(kw) * bhi(qw);
      }
      float lgv = ok ? acc * 0.125f : NEGINF;
      float cm = lgv;
      for (int o = 32; o; o >>= 1) cm = fmaxf(cm, __shfl_xor(cm, o));
      if (cm == NEGINF) continue;
      const float mn = fmaxf(m_i[rr], cm);
      float pv = __expf(lgv - mn);
      float rs = pv;
      for (int o = 32; o; o >>= 1) rs += __shfl_xor(rs, o);
      const float alpha = __expf(m_i[rr] - mn);
      m_i[rr] = mn;
      l_i[rr] = l_i[rr] * alpha + rs;
      float psg = ih ? pv : -pv;
      float ya = y_i[rr] * alpha;
      for (int s = 0; s < 64; ++s) {
        float ps = __shfl(psg, s);
        int sel = ps > 0.f ? 1 : 0;
        float va = b2f(Vm[sel][s * 66 + lane]);
        ya += fabsf(ps) * va;
      }
      y_i[rr] = ya;
    }
  }
#pragma unroll
  for (int rr = 0; rr < 16; ++rr) {
    const int trow = t0 + wv * 16 + rr;
    float ol = l_i[rr];
    y[((size_t)(2048 + b * 1024 + trow)) * 1024 + h * 64 + lane] = f2b(ol > 0.f ? y_i[rr] / ol : 0.f);
  }
}

// ---------------------------------------------------------------------------
extern "C" void kernel_launch(void* const* d_in, const int* in_sizes, int n_in,
                              void* d_out, int out_size, void* d_ws, size_t ws_size,
                              hipStream_t stream) {
  const void* xs = d_in[0];
  const void* xh = d_in[1];
  const void* cc = d_in[2];
  const void* mstar = d_in[3];
  const void* mhat = d_in[4];
  const void* mdep = d_in[5];
  const void* ng = d_in[6];
  const void* nb = d_in[7];
  const void* Wq = d_in[8];
  const void* bq = d_in[9];
  const void* Wkv = d_in[10];
  const void* bkv = d_in[11];
  const void* Wco = d_in[12];
  const void* bco = d_in[13];
  const void* Wada = d_in[14];
  const void* bada = d_in[15];
  const void* Wqkv = d_in[16];
  const void* bqkv = d_in[17];
  const void* Wo = d_in[18];
  const void* bo = d_in[19];
  const void* W1 = d_in[20];
  const void* b1 = d_in[21];
  const void* W2 = d_in[22];
  const void* b2 = d_in[23];
  (void)in_sizes; (void)n_in; (void)out_size; (void)ws_size;

  char* ws = (char*)d_ws;
  size_t off = 0;
  auto alloc = [&](size_t bytes) -> char* {
    char* p = ws + off;
    off += (bytes + 255) & ~(size_t)255;
    return p;
  };
  int* flags = (int*)alloc(256);
  // converted small tensors
  unsigned short* ngb = (unsigned short*)alloc(1024 * 2);
  unsigned short* nbb = (unsigned short*)alloc(1024 * 2);
  unsigned short* bqb = (unsigned short*)alloc(1024 * 2);
  unsigned short* bkvb = (unsigned short*)alloc(2048 * 2);
  unsigned short* bcob = (unsigned short*)alloc(1024 * 2);
  unsigned short* badab = (unsigned short*)alloc(6144 * 2);
  unsigned short* bqkvb = (unsigned short*)alloc(3072 * 2);
  unsigned short* bob = (unsigned short*)alloc(1024 * 2);
  unsigned short* b1b = (unsigned short*)alloc(4096 * 2);
  unsigned short* b2b = (unsigned short*)alloc(1024 * 2);
  // transposed weights (persistent)
  unsigned short* WqT = (unsigned short*)alloc(1048576ull * 2);
  unsigned short* WkvT = (unsigned short*)alloc(2097152ull * 2);
  unsigned short* WcoT = (unsigned short*)alloc(1048576ull * 2);
  unsigned short* WadaT = (unsigned short*)alloc(6291456ull * 2);
  unsigned short* WqkvT = (unsigned short*)alloc(3145728ull * 2);
  unsigned short* WoT = (unsigned short*)alloc(1048576ull * 2);
  unsigned short* W1T = (unsigned short*)alloc(4194304ull * 2);
  unsigned short* W2T = (unsigned short*)alloc(4194304ull * 2);
  // activations
  unsigned short* xsb = (unsigned short*)alloc(2097152ull * 2);
  unsigned short* xhb = (unsigned short*)alloc(2097152ull * 2);
  unsigned short* xn = (unsigned short*)alloc(4194304ull * 2);   // also yca
  unsigned short* qb = (unsigned short*)alloc(4194304ull * 2);   // also silub
  unsigned short* kvb = (unsigned short*)alloc(1048576ull * 2);
  unsigned short* gada = (unsigned short*)alloc(25165824ull * 2);  // wstage aliases front
  unsigned short* msb = (unsigned short*)alloc(4194304ull * 2);  // also yat
  unsigned short* qkvb = (unsigned short*)alloc(12582912ull * 2);
  float* x1 = (float*)alloc(4194304ull * 4);
  unsigned short* hid = (unsigned short*)alloc(16777216ull * 2); // ccb + lnx alias front
  unsigned long long* sbits = (unsigned long long*)alloc(2048ull * 16 * 8);
  unsigned long long* hbits = (unsigned long long*)alloc(2048ull * 16 * 8);
  unsigned long long* dbits = (unsigned long long*)alloc(2048ull * 16 * 8);

  unsigned short* wstage = gada;              // weight staging, dead before gada written
  unsigned short* ccb = hid;                  // 524288 elems, dead before hid written
  unsigned short* lnx = hid + 1048576;        // 4194304 elems, dead before hid written
  unsigned short* yca = xn;
  unsigned short* silub = qb;
  unsigned short* yat = msb;

  dim3 blk(256);
  detect_flags<<<1, blk, 0, stream>>>((const unsigned int*)xs, (const unsigned int*)mdep, flags);

  // convert activations + small tensors
  cvt_bf16<<<2048, blk, 0, stream>>>(xs, xsb, 2097152, flags);
  cvt_bf16<<<2048, blk, 0, stream>>>(xh, xhb, 2097152, flags);
  cvt_bf16<<<512, blk, 0, stream>>>(cc, ccb, 524288, flags);
  cvt_bf16<<<1, blk, 0, stream>>>(ng, ngb, 1024, flags);
  cvt_bf16<<<1, blk, 0, stream>>>(nb, nbb, 1024, flags);
  cvt_bf16<<<1, blk, 0, stream>>>(bq, bqb, 1024, flags);
  cvt_bf16<<<2, blk, 0, stream>>>(bkv, bkvb, 2048, flags);
  cvt_bf16<<<1, blk, 0, stream>>>(bco, bcob, 1024, flags);
  cvt_bf16<<<6, blk, 0, stream>>>(bada, badab, 6144, flags);
  cvt_bf16<<<3, blk, 0, stream>>>(bqkv, bqkvb, 3072, flags);
  cvt_bf16<<<1, blk, 0, stream>>>(bo, bob, 1024, flags);
  cvt_bf16<<<4, blk, 0, stream>>>(b1, b1b, 4096, flags);
  cvt_bf16<<<1, blk, 0, stream>>>(b2, b2b, 1024, flags);

  // stage + transpose weights (sequential reuse of wstage)
  cvt_bf16<<<1024, blk, 0, stream>>>(Wq, wstage, 1048576, flags);
  transpose_bf16<<<dim3(32, 32), blk, 0, stream>>>(wstage, WqT, 1024, 1024);
  cvt_bf16<<<2048, blk, 0, stream>>>(Wkv, wstage, 2097152, flags);
  transpose_bf16<<<dim3(32, 64), blk, 0, stream>>>(wstage, WkvT, 1024, 2048);
  cvt_bf16<<<1024, blk, 0, stream>>>(Wco, wstage, 1048576, flags);
  transpose_bf16<<<dim3(32, 32), blk, 0, stream>>>(wstage, WcoT, 1024, 1024);
  cvt_bf16<<<6144, blk, 0, stream>>>(Wada, wstage, 6291456, flags);
  transpose_bf16<<<dim3(32, 192), blk, 0, stream>>>(wstage, WadaT, 1024, 6144);
  cvt_bf16<<<3072, blk, 0, stream>>>(Wqkv, wstage, 3145728, flags);
  transpose_bf16<<<dim3(32, 96), blk, 0, stream>>>(wstage, WqkvT, 1024, 3072);
  cvt_bf16<<<1024, blk, 0, stream>>>(Wo, wstage, 1048576, flags);
  transpose_bf16<<<dim3(32, 32), blk, 0, stream>>>(wstage, WoT, 1024, 1024);
  cvt_bf16<<<4096, blk, 0, stream>>>(W1, wstage, 4194304, flags);
  transpose_bf16<<<dim3(32, 128), blk, 0, stream>>>(wstage, W1T, 1024, 4096);
  cvt_bf16<<<4096, blk, 0, stream>>>(W2, wstage, 4194304, flags);
  transpose_bf16<<<dim3(128, 32), blk, 0, stream>>>(wstage, W2T, 4096, 1024);

  pack_mask<<<512, blk, 0, stream>>>(mstar, sbits, flags);
  pack_mask<<<512, blk, 0, stream>>>(mhat, hbits, flags);
  pack_mask<<<512, blk, 0, stream>>>(mdep, dbits, flags);

  ln_affine<<<4096, blk, 0, stream>>>(xsb, xhb, ngb, nbb, lnx, xn);
  gemm_bt<EPI_BF16><<<dim3(32, 8), blk, 0, stream>>>(xn, WqT, bqb, qb, 4096, 1024, 1024, nullptr, nullptr, nullptr, nullptr);
  gemm_bt<EPI_BF16><<<dim3(4, 16), blk, 0, stream>>>(ccb, WkvT, bkvb, kvb, 512, 2048, 1024, nullptr, nullptr, nullptr, nullptr);
  cross_attn<<<512, blk, 0, stream>>>(qb, kvb, yca);
  gemm_bt<EPI_SILU><<<dim3(32, 8), blk, 0, stream>>>(yca, WcoT, bcob, silub, 4096, 1024, 1024, nullptr, nullptr, nullptr, nullptr);
  gemm_bt<EPI_BF16><<<dim3(32, 48), blk, 0, stream>>>(silub, WadaT, badab, gada, 4096, 6144, 1024, nullptr, nullptr, nullptr, nullptr);
  mod_ms<<<4096, blk, 0, stream>>>(lnx, gada, msb);
  gemm_bt<EPI_BF16><<<dim3(32, 24), blk, 0, stream>>>(msb, WqkvT, bqkvb, qkvb, 4096, 3072, 1024, nullptr, nullptr, nullptr, nullptr);
  star_attn<<<512, blk, 0, stream>>>(qkvb, dbits, yat);
  hat_attn<<<512, blk, 0, stream>>>(qkvb, sbits, hbits, dbits, yat);
  gemm_bt<EPI_GATE_XRES><<<dim3(32, 8), blk, 0, stream>>>(yat, WoT, bob, x1, 4096, 1024, 1024, gada + 2048, xsb, xhb, nullptr);
  ln_mod<<<4096, blk, 0, stream>>>(x1, gada, msb);
  gemm_bt<EPI_GELU><<<dim3(32, 32), blk, 0, stream>>>(msb, W1T, b1b, hid, 4096, 4096, 1024, nullptr, nullptr, nullptr, nullptr);
  gemm_bt<EPI_GATE_OUT><<<dim3(32, 8), blk, 0, stream>>>(hid, W2T, b2b, d_out, 4096, 1024, 4096, gada + 5120, x1, nullptr, flags);
}

// Round 3
// 893.323 us; speedup vs baseline: 4.7120x; 4.7120x over previous
//
#include <hip/hip_runtime.h>
#include <hip/hip_bf16.h>
#include <stdint.h>

#define DEVI __device__ __forceinline__

typedef __bf16 bf16x8 __attribute__((ext_vector_type(8)));
typedef float f32x4 __attribute__((ext_vector_type(4)));

DEVI float b2f(unsigned short u) { union { unsigned int i; float f; } v; v.i = ((unsigned int)u) << 16; return v.f; }
DEVI unsigned short f2b(float f) {
  union { unsigned int i; float f; } v; v.f = f;
  unsigned int r = (v.i + 0x7fffu + ((v.i >> 16) & 1u)) >> 16;
  return (unsigned short)r;
}

#define NEGINF (-__builtin_inff())

// ---------------------------------------------------------------------------
// Runtime dtype detection (device-side, deterministic, graph-safe).
// flags[0]: 1 if float tensors are f32, 0 if bf16.
// flags[1]: 1 if bool masks are byte-packed, 0 if int32.
// ---------------------------------------------------------------------------
__global__ __launch_bounds__(256) void detect_flags(
    const unsigned int* __restrict__ xw, const unsigned int* __restrict__ mw,
    int* __restrict__ flags) {
  const int t = threadIdx.x;
  int cnt = 0, big = 0;
  for (int i = t; i < 4096; i += 256) {
    unsigned int w = xw[i];
    unsigned short lo = (unsigned short)(w & 0xffffu);
    float f = b2f(lo);
    float a = fabsf(f);
    bool plaus = (lo == 0) || (a >= 1e-8f && a <= 256.f);
    cnt += plaus ? 1 : 0;
    big |= (mw[i] > 1u) ? 1 : 0;
  }
  for (int o = 32; o; o >>= 1) { cnt += __shfl_down(cnt, o); big |= __shfl_down(big, o); }
  __shared__ int sc[4], sb[4];
  if ((t & 63) == 0) { sc[t >> 6] = cnt; sb[t >> 6] = big; }
  __syncthreads();
  if (t == 0) {
    flags[0] = (sc[0] + sc[1] + sc[2] + sc[3] < 2048) ? 1 : 0;
    flags[1] = (sb[0] | sb[1] | sb[2] | sb[3]);
  }
}

// Convert a float tensor (f32 or bf16 per flags[0]) into canonical bf16.
__global__ __launch_bounds__(256) void cvt_bf16(
    const void* __restrict__ src, unsigned short* __restrict__ dst, int n,
    const int* __restrict__ flags) {
  const int f32mode = flags[0];
  int idx = (blockIdx.x * 256 + threadIdx.x) * 4;
  if (idx >= n) return;
  if (f32mode) {
    const float* s = (const float*)src;
    float4 v = *(const float4*)(s + idx);
    dst[idx] = f2b(v.x); dst[idx + 1] = f2b(v.y);
    dst[idx + 2] = f2b(v.z); dst[idx + 3] = f2b(v.w);
  } else {
    *(uint2*)(dst + idx) = *(const uint2*)((const unsigned short*)src + idx);
  }
}

// ---------------------------------------------------------------------------
// Weight transpose (K,N) -> (N,K), bf16
// ---------------------------------------------------------------------------
__global__ __launch_bounds__(256) void transpose_bf16(
    const unsigned short* __restrict__ W, unsigned short* __restrict__ WT, int K, int N) {
  __shared__ __attribute__((aligned(16))) unsigned short tile[32][33];
  int k0 = blockIdx.x * 32, n0 = blockIdx.y * 32;
  int tx = threadIdx.x & 31, ty = threadIdx.x >> 5;
  for (int i = ty; i < 32; i += 8) tile[i][tx] = W[(size_t)(k0 + i) * N + n0 + tx];
  __syncthreads();
  for (int i = ty; i < 32; i += 8) WT[(size_t)(n0 + i) * K + k0 + tx] = tile[tx][i];
}

// ---------------------------------------------------------------------------
// Pack bool masks (2048 rows x 1024) into 64-bit words (2048 x 16).
// ---------------------------------------------------------------------------
__global__ __launch_bounds__(256) void pack_mask(
    const void* __restrict__ m, unsigned long long* __restrict__ bits,
    const int* __restrict__ flags) {
  const int bytemode = flags[1];
  int wv = blockIdx.x * 4 + (threadIdx.x >> 6);
  int lane = threadIdx.x & 63;
  for (int w = 0; w < 16; ++w) {
    int v;
    if (bytemode) v = ((const unsigned char*)m)[(size_t)wv * 1024 + w * 64 + lane];
    else          v = ((const int*)m)[(size_t)wv * 1024 + w * 64 + lane];
    unsigned long long b = __ballot(v != 0);
    if (lane == 0) bits[(size_t)wv * 16 + w] = b;
  }
}

// ---------------------------------------------------------------------------
// LayerNorm (eps 1e-6, no affine); writes lnx and ncond-affine xn.
// ---------------------------------------------------------------------------
__global__ __launch_bounds__(256) void ln_affine(
    const unsigned short* __restrict__ xs, const unsigned short* __restrict__ xh,
    const unsigned short* __restrict__ gw, const unsigned short* __restrict__ bw,
    unsigned short* __restrict__ lnx, unsigned short* __restrict__ xn) {
  const int row = blockIdx.x;
  const unsigned short* xp = (row < 2048) ? xs + (size_t)row * 1024 : xh + (size_t)(row - 2048) * 1024;
  const int t = threadIdx.x;
  float v[4]; float s = 0.f, ss = 0.f;
#pragma unroll
  for (int i = 0; i < 4; ++i) { float x = b2f(xp[i * 256 + t]); v[i] = x; s += x; ss += x * x; }
  for (int o = 32; o; o >>= 1) { s += __shfl_down(s, o); ss += __shfl_down(ss, o); }
  __shared__ float red[2][4];
  const int wv = t >> 6, lane = t & 63;
  if (lane == 0) { red[0][wv] = s; red[1][wv] = ss; }
  __syncthreads();
  s = red[0][0] + red[0][1] + red[0][2] + red[0][3];
  ss = red[1][0] + red[1][1] + red[1][2] + red[1][3];
  const float mean = s * (1.f / 1024.f);
  const float var = fmaxf(ss * (1.f / 1024.f) - mean * mean, 0.f);
  const float rstd = rsqrtf(var + 1e-6f);
  const size_t ro = (size_t)row * 1024;
#pragma unroll
  for (int i = 0; i < 4; ++i) {
    int c = i * 256 + t;
    float n = (v[i] - mean) * rstd;
    lnx[ro + c] = f2b(n);
    xn[ro + c] = f2b(n * b2f(gw[c]) + b2f(bw[c]));
  }
}

// ms = lnx * (1 + g[1C]) + g[0C]
__global__ __launch_bounds__(256) void mod_ms(
    const unsigned short* __restrict__ lnx, const unsigned short* __restrict__ gada,
    unsigned short* __restrict__ ms) {
  const size_t idx = ((size_t)blockIdx.x * 256 + threadIdx.x) * 4;
  const int row = (int)(idx >> 10), c = (int)(idx & 1023);
  const size_t gb = (size_t)row * 6144;
#pragma unroll
  for (int i = 0; i < 4; ++i) {
    float sh = b2f(gada[gb + c + i]);
    float sc = b2f(gada[gb + 1024 + c + i]);
    ms[idx + i] = f2b(b2f(lnx[idx + i]) * (1.f + sc) + sh);
  }
}

// m2 = LN(x1) * (1 + g[4C]) + g[3C]   (x1 is f32)
__global__ __launch_bounds__(256) void ln_mod(
    const float* __restrict__ x1, const unsigned short* __restrict__ gada,
    unsigned short* __restrict__ m2) {
  const int row = blockIdx.x;
  const float* xp = x1 + (size_t)row * 1024;
  const int t = threadIdx.x;
  float v[4]; float s = 0.f, ss = 0.f;
#pragma unroll
  for (int i = 0; i < 4; ++i) { float x = xp[i * 256 + t]; v[i] = x; s += x; ss += x * x; }
  for (int o = 32; o; o >>= 1) { s += __shfl_down(s, o); ss += __shfl_down(ss, o); }
  __shared__ float red[2][4];
  const int wv = t >> 6, lane = t & 63;
  if (lane == 0) { red[0][wv] = s; red[1][wv] = ss; }
  __syncthreads();
  s = red[0][0] + red[0][1] + red[0][2] + red[0][3];
  ss = red[1][0] + red[1][1] + red[1][2] + red[1][3];
  const float mean = s * (1.f / 1024.f);
  const float var = fmaxf(ss * (1.f / 1024.f) - mean * mean, 0.f);
  const float rstd = rsqrtf(var + 1e-6f);
  const size_t gb = (size_t)row * 6144;
#pragma unroll
  for (int i = 0; i < 4; ++i) {
    int c = i * 256 + t;
    float n = (v[i] - mean) * rstd;
    float sh = b2f(gada[gb + 3072 + c]);
    float sc = b2f(gada[gb + 4096 + c]);
    m2[(size_t)row * 1024 + c] = f2b(n * (1.f + sc) + sh);
  }
}

// ---------------------------------------------------------------------------
// MFMA GEMM: C[M,N] = A[M,K] @ BT[N,K]^T + bias, fused epilogues.
// ---------------------------------------------------------------------------
enum { EPI_BF16 = 0, EPI_SILU, EPI_GELU, EPI_GATE_XRES, EPI_GATE_OUT };

template <int EPI>
__global__ __launch_bounds__(256) void gemm_bt(
    const unsigned short* __restrict__ A, const unsigned short* __restrict__ BT,
    const unsigned short* __restrict__ bias, void* __restrict__ out,
    int M, int N, int K,
    const unsigned short* __restrict__ gate,
    const void* __restrict__ res0, const void* __restrict__ res1,
    const int* __restrict__ oflags) {
  constexpr int LDK = 40;
  __shared__ __attribute__((aligned(16))) unsigned short As[128 * LDK];
  __shared__ __attribute__((aligned(16))) unsigned short Bs[128 * LDK];
  const int m0 = blockIdx.x * 128, n0 = blockIdx.y * 128;
  const int t = threadIdx.x;
  const int wave = t >> 6, lane = t & 63;
  const int wm = (wave >> 1) * 64, wn = (wave & 1) * 64;
  const int l16 = lane & 15, quad = lane >> 4;
  f32x4 acc[4][4] = {};

  const int row_l = t >> 2, col_l = (t & 3) * 8;
  const unsigned short* ga = A + (size_t)(m0 + row_l) * K + col_l;
  const unsigned short* gb = BT + (size_t)(n0 + row_l) * K + col_l;

  for (int k0 = 0; k0 < K; k0 += 32) {
    __syncthreads();
    uint4 a0 = *(const uint4*)(ga + k0);
    uint4 a1 = *(const uint4*)(ga + (size_t)64 * K + k0);
    uint4 b0 = *(const uint4*)(gb + k0);
    uint4 b1 = *(const uint4*)(gb + (size_t)64 * K + k0);
    *(uint4*)&As[row_l * LDK + col_l] = a0;
    *(uint4*)&As[(row_l + 64) * LDK + col_l] = a1;
    *(uint4*)&Bs[row_l * LDK + col_l] = b0;
    *(uint4*)&Bs[(row_l + 64) * LDK + col_l] = b1;
    __syncthreads();
    bf16x8 af[4], bf[4];
#pragma unroll
    for (int i = 0; i < 4; ++i) af[i] = *(const bf16x8*)(const void*)&As[(wm + i * 16 + l16) * LDK + quad * 8];
#pragma unroll
    for (int j = 0; j < 4; ++j) bf[j] = *(const bf16x8*)(const void*)&Bs[(wn + j * 16 + l16) * LDK + quad * 8];
#pragma unroll
    for (int i = 0; i < 4; ++i)
#pragma unroll
      for (int j = 0; j < 4; ++j)
        acc[i][j] = __builtin_amdgcn_mfma_f32_16x16x32_bf16(af[i], bf[j], acc[i][j], 0, 0, 0);
  }

#pragma unroll
  for (int i = 0; i < 4; ++i) {
    const int gm = m0 + wm + i * 16 + quad * 4;
#pragma unroll
    for (int j = 0; j < 4; ++j) {
      const int gn = n0 + wn + j * 16 + l16;
      const float bv = b2f(bias[gn]);
#pragma unroll
      for (int r = 0; r < 4; ++r) {
        const int gmr = gm + r;
        float v = acc[i][j][r] + bv;
        const size_t oi = (size_t)gmr * N + gn;
        if constexpr (EPI == EPI_BF16) {
          ((unsigned short*)out)[oi] = f2b(v);
        } else if constexpr (EPI == EPI_SILU) {
          ((unsigned short*)out)[oi] = f2b(v / (1.f + __expf(-v)));
        } else if constexpr (EPI == EPI_GELU) {
          float u = 0.7978845608028654f * (v + 0.044715f * v * v * v);
          float th = 1.f - 2.f / (__expf(2.f * u) + 1.f);
          ((unsigned short*)out)[oi] = f2b(0.5f * v * (1.f + th));
        } else if constexpr (EPI == EPI_GATE_XRES) {
          float g = b2f(gate[(size_t)gmr * 6144 + gn]);
          const unsigned short* xr = (gmr < 2048) ? (const unsigned short*)res0 : (const unsigned short*)res1;
          float x = b2f(xr[(size_t)(gmr & 2047) * 1024 + gn]);
          ((float*)out)[oi] = x + g * v;
        } else {
          float g = b2f(gate[(size_t)gmr * 6144 + gn]);
          float x = ((const float*)res0)[oi];
          float r2 = x + g * v;
          if (oflags[0]) ((float*)out)[oi] = r2;
          else ((unsigned short*)out)[oi] = f2b(r2);
        }
      }
    }
  }
}

// ---------------------------------------------------------------------------
// MFMA flash attention kernels.
// Layouts (16x16x32 bf16, verified): A[m][k]: m=lane&15, k=quad*8+j;
// B[n][k]: n=lane&15, k=quad*8+j; C/D: col=lane&15, row=quad*4+reg.
// Q A-frags and K B-frags load straight from global (d contiguous).
// V transposed into LDS (Vt[d][key]) so PV B-frags are ds_read_b128.
// P round-trips through wave-private LDS (C-layout -> A-layout).
// ---------------------------------------------------------------------------

// Cross attention: 64 q-rows/block, 256 keys (4 chunks), no mask.
__global__ __launch_bounds__(256) void cross_attn_mfma(
    const unsigned short* __restrict__ q, const unsigned short* __restrict__ kv,
    unsigned short* __restrict__ y) {
  constexpr int LDV = 72;
  __shared__ __attribute__((aligned(16))) unsigned short Vt[64 * LDV];
  __shared__ __attribute__((aligned(16))) unsigned short Ps[4][16 * LDV];
  const int bid = blockIdx.x;
  const int tt = bid & 15, h = (bid >> 4) & 15, b = (bid >> 8) & 1, st = bid >> 9;
  const int t = threadIdx.x, wv = t >> 6, lane = t & 63;
  const int l16 = lane & 15, quad = lane >> 4;
  const int rowbase = st * 2048 + b * 1024 + tt * 64 + wv * 16;
  const unsigned short* qp = q + (size_t)(rowbase + l16) * 1024 + h * 64 + quad * 8;
  bf16x8 aq0 = *(const bf16x8*)(qp);
  bf16x8 aq1 = *(const bf16x8*)(qp + 32);
  const unsigned short* kb = kv + (size_t)b * (256 * 2048) + h * 64;
  const unsigned short* vb = kb + 1024;
  float m_st[4] = {NEGINF, NEGINF, NEGINF, NEGINF};
  float l_st[4] = {0.f, 0.f, 0.f, 0.f};
  f32x4 o[4] = {};
  for (int ck = 0; ck < 4; ++ck) {
    const int s0 = ck * 64;
    __syncthreads();
#pragma unroll
    for (int it = 0; it < 2; ++it) {
      int key = it * 32 + (t >> 3), d0 = (t & 7) * 8;
      uint4 vvd = *(const uint4*)(vb + (size_t)(s0 + key) * 2048 + d0);
      const unsigned short* e = (const unsigned short*)&vvd;
#pragma unroll
      for (int i = 0; i < 8; ++i) Vt[(d0 + i) * LDV + key] = e[i];
    }
    __syncthreads();
    f32x4 s[4];
#pragma unroll
    for (int j = 0; j < 4; ++j) {
      const unsigned short* kp = kb + (size_t)(s0 + j * 16 + l16) * 2048 + quad * 8;
      bf16x8 bk0 = *(const bf16x8*)(kp);
      bf16x8 bk1 = *(const bf16x8*)(kp + 32);
      f32x4 z = {};
      z = __builtin_amdgcn_mfma_f32_16x16x32_bf16(aq0, bk0, z, 0, 0, 0);
      z = __builtin_amdgcn_mfma_f32_16x16x32_bf16(aq1, bk1, z, 0, 0, 0);
      s[j] = z;
    }
#pragma unroll
    for (int r = 0; r < 4; ++r) {
      float mx = NEGINF;
#pragma unroll
      for (int j = 0; j < 4; ++j) {
        float sv = s[j][r] * 0.125f;
        s[j][r] = sv;
        mx = fmaxf(mx, sv);
      }
#pragma unroll
      for (int o2 = 8; o2; o2 >>= 1) mx = fmaxf(mx, __shfl_xor(mx, o2));
      const float mn = fmaxf(m_st[r], mx);
      const float alpha = __expf(m_st[r] - mn);  // m_st=-inf first: exp(-inf)=0
      float rs = 0.f;
#pragma unroll
      for (int j = 0; j < 4; ++j) {
        float p = __expf(s[j][r] - mn);
        s[j][r] = p;
        rs += p;
      }
#pragma unroll
      for (int o2 = 8; o2; o2 >>= 1) rs += __shfl_xor(rs, o2);
      m_st[r] = mn;
      l_st[r] = l_st[r] * alpha + rs;
#pragma unroll
      for (int jd = 0; jd < 4; ++jd) o[jd][r] *= alpha;
#pragma unroll
      for (int j = 0; j < 4; ++j)
        Ps[wv][(quad * 4 + r) * LDV + j * 16 + l16] = f2b(s[j][r]);
    }
    bf16x8 ap0 = *(const bf16x8*)(const void*)&Ps[wv][l16 * LDV + quad * 8];
    bf16x8 ap1 = *(const bf16x8*)(const void*)&Ps[wv][l16 * LDV + 32 + quad * 8];
#pragma unroll
    for (int jd = 0; jd < 4; ++jd) {
      bf16x8 bv0 = *(const bf16x8*)(const void*)&Vt[(jd * 16 + l16) * LDV + quad * 8];
      bf16x8 bv1 = *(const bf16x8*)(const void*)&Vt[(jd * 16 + l16) * LDV + 32 + quad * 8];
      o[jd] = __builtin_amdgcn_mfma_f32_16x16x32_bf16(ap0, bv0, o[jd], 0, 0, 0);
      o[jd] = __builtin_amdgcn_mfma_f32_16x16x32_bf16(ap1, bv1, o[jd], 0, 0, 0);
    }
  }
#pragma unroll
  for (int r = 0; r < 4; ++r) {
    const float inv = (l_st[r] > 0.f) ? 1.f / l_st[r] : 0.f;
#pragma unroll
    for (int jd = 0; jd < 4; ++jd)
      y[(size_t)(rowbase + quad * 4 + r) * 1024 + h * 64 + jd * 16 + l16] = f2b(o[jd][r] * inv);
  }
}

// Star: causal + dep mask, chunks 0..tt.
__global__ __launch_bounds__(256) void star_attn_mfma(
    const unsigned short* __restrict__ qkv, const unsigned long long* __restrict__ depb,
    unsigned short* __restrict__ y) {
  constexpr int LDV = 72;
  __shared__ __attribute__((aligned(16))) unsigned short Vt[64 * LDV];
  __shared__ __attribute__((aligned(16))) unsigned short Ps[4][16 * LDV];
  const int bid = blockIdx.x;
  const int tt = bid & 15, h = (bid >> 4) & 15, b = bid >> 8;
  const int t = threadIdx.x, wv = t >> 6, lane = t & 63;
  const int l16 = lane & 15, quad = lane >> 4;
  const int t0 = tt * 64;
  const int rowbase = b * 1024 + t0 + wv * 16;
  const unsigned short* qp = qkv + (size_t)(rowbase + l16) * 3072 + h * 64 + quad * 8;
  bf16x8 aq0 = *(const bf16x8*)(qp);
  bf16x8 aq1 = *(const bf16x8*)(qp + 32);
  const unsigned short* kb = qkv + (size_t)(b * 1024) * 3072 + 1024 + h * 64;
  const unsigned short* vb = kb + 1024;
  float m_st[4] = {NEGINF, NEGINF, NEGINF, NEGINF};
  float l_st[4] = {0.f, 0.f, 0.f, 0.f};
  f32x4 o[4] = {};
  for (int ck = 0; ck <= tt; ++ck) {
    const int s0 = ck * 64;
    __syncthreads();
#pragma unroll
    for (int it = 0; it < 2; ++it) {
      int key = it * 32 + (t >> 3), d0 = (t & 7) * 8;
      uint4 vvd = *(const uint4*)(vb + (size_t)(s0 + key) * 3072 + d0);
      const unsigned short* e = (const unsigned short*)&vvd;
#pragma unroll
      for (int i = 0; i < 8; ++i) Vt[(d0 + i) * LDV + key] = e[i];
    }
    __syncthreads();
    unsigned long long dwv[4];
#pragma unroll
    for (int r = 0; r < 4; ++r)
      dwv[r] = depb[(size_t)(rowbase + quad * 4 + r) * 16 + ck];
    f32x4 s[4];
#pragma unroll
    for (int j = 0; j < 4; ++j) {
      const unsigned short* kp = kb + (size_t)(s0 + j * 16 + l16) * 3072 + quad * 8;
      bf16x8 bk0 = *(const bf16x8*)(kp);
      bf16x8 bk1 = *(const bf16x8*)(kp + 32);
      f32x4 z = {};
      z = __builtin_amdgcn_mfma_f32_16x16x32_bf16(aq0, bk0, z, 0, 0, 0);
      z = __builtin_amdgcn_mfma_f32_16x16x32_bf16(aq1, bk1, z, 0, 0, 0);
      s[j] = z;
    }
#pragma unroll
    for (int r = 0; r < 4; ++r) {
      const int trow = t0 + wv * 16 + quad * 4 + r;
      float mx = NEGINF;
#pragma unroll
      for (int j = 0; j < 4; ++j) {
        const int kg = s0 + j * 16 + l16;
        bool ok = (kg <= trow) && ((dwv[r] >> (j * 16 + l16)) & 1ull);
        float sv = ok ? s[j][r] * 0.125f : NEGINF;
        s[j][r] = sv;
        mx = fmaxf(mx, sv);
      }
#pragma unroll
      for (int o2 = 8; o2; o2 >>= 1) mx = fmaxf(mx, __shfl_xor(mx, o2));
      const float mn = fmaxf(m_st[r], mx);
      const bool dead = (mn == NEGINF);
      const float alpha = dead ? 1.f : __expf(m_st[r] - mn);
      float rs = 0.f;
#pragma unroll
      for (int j = 0; j < 4; ++j) {
        float p = dead ? 0.f : __expf(s[j][r] - mn);
        s[j][r] = p;
        rs += p;
      }
#pragma unroll
      for (int o2 = 8; o2; o2 >>= 1) rs += __shfl_xor(rs, o2);
      m_st[r] = mn;
      l_st[r] = l_st[r] * alpha + rs;
#pragma unroll
      for (int jd = 0; jd < 4; ++jd) o[jd][r] *= alpha;
#pragma unroll
      for (int j = 0; j < 4; ++j)
        Ps[wv][(quad * 4 + r) * LDV + j * 16 + l16] = f2b(s[j][r]);
    }
    bf16x8 ap0 = *(const bf16x8*)(const void*)&Ps[wv][l16 * LDV + quad * 8];
    bf16x8 ap1 = *(const bf16x8*)(const void*)&Ps[wv][l16 * LDV + 32 + quad * 8];
#pragma unroll
    for (int jd = 0; jd < 4; ++jd) {
      bf16x8 bv0 = *(const bf16x8*)(const void*)&Vt[(jd * 16 + l16) * LDV + quad * 8];
      bf16x8 bv1 = *(const bf16x8*)(const void*)&Vt[(jd * 16 + l16) * LDV + 32 + quad * 8];
      o[jd] = __builtin_amdgcn_mfma_f32_16x16x32_bf16(ap0, bv0, o[jd], 0, 0, 0);
      o[jd] = __builtin_amdgcn_mfma_f32_16x16x32_bf16(ap1, bv1, o[jd], 0, 0, 0);
    }
  }
#pragma unroll
  for (int r = 0; r < 4; ++r) {
    const float inv = (l_st[r] > 0.f) ? 1.f / l_st[r] : 0.f;
#pragma unroll
    for (int jd = 0; jd < 4; ++jd)
      y[(size_t)(rowbase + quad * 4 + r) * 1024 + h * 64 + jd * 16 + l16] = f2b(o[jd][r] * inv);
  }
}

// Hat: concat [K_star;K_hat] along keys (masks disjoint: chunk> vs chunk==),
// 128-key flash pass per chunk == reference's merged-logit softmax.
__global__ __launch_bounds__(256) void hat_attn_mfma(
    const unsigned short* __restrict__ qkv,
    const unsigned long long* __restrict__ starb, const unsigned long long* __restrict__ hatb,
    const unsigned long long* __restrict__ depb, unsigned short* __restrict__ y) {
  constexpr int LDV = 136;
  __shared__ __attribute__((aligned(16))) unsigned short Vt[64 * LDV];
  __shared__ __attribute__((aligned(16))) unsigned short Ps[4][16 * LDV];
  const int bid = blockIdx.x;
  const int tt = bid & 15, h = (bid >> 4) & 15, b = bid >> 8;
  const int t = threadIdx.x, wv = t >> 6, lane = t & 63;
  const int l16 = lane & 15, quad = lane >> 4;
  const int t0 = tt * 64;
  const int rowbase = b * 1024 + t0 + wv * 16;  // mask/star-space row
  const unsigned short* qp = qkv + (size_t)(2048 + rowbase + l16) * 3072 + h * 64 + quad * 8;
  bf16x8 aq0 = *(const bf16x8*)(qp);
  bf16x8 aq1 = *(const bf16x8*)(qp + 32);
  const unsigned short* ksb = qkv + (size_t)(b * 1024) * 3072 + 1024 + h * 64;
  const unsigned short* vsb = ksb + 1024;
  const unsigned short* khb = qkv + (size_t)(2048 + b * 1024) * 3072 + 1024 + h * 64;
  const unsigned short* vhb = khb + 1024;
  float m_st[4] = {NEGINF, NEGINF, NEGINF, NEGINF};
  float l_st[4] = {0.f, 0.f, 0.f, 0.f};
  f32x4 o[4] = {};
  for (int ck = 0; ck < 16; ++ck) {
    const int s0 = ck * 64;
    __syncthreads();
#pragma unroll
    for (int it = 0; it < 4; ++it) {
      int key = (it & 1) * 32 + (t >> 3), d0 = (t & 7) * 8;
      const unsigned short* src = (it < 2) ? vsb : vhb;
      int dk = (it < 2 ? 0 : 64) + key;
      uint4 vvd = *(const uint4*)(src + (size_t)(s0 + key) * 3072 + d0);
      const unsigned short* e = (const unsigned short*)&vvd;
#pragma unroll
      for (int i = 0; i < 8; ++i) Vt[(d0 + i) * LDV + dk] = e[i];
    }
    __syncthreads();
    unsigned long long swv[4], hwv[4], dwv[4];
#pragma unroll
    for (int r = 0; r < 4; ++r) {
      const size_t mrow = (size_t)(rowbase + quad * 4 + r) * 16 + ck;
      swv[r] = starb[mrow]; hwv[r] = hatb[mrow]; dwv[r] = depb[mrow];
    }
    f32x4 s[8];
#pragma unroll
    for (int j = 0; j < 8; ++j) {
      const unsigned short* base = (j < 4) ? ksb : khb;
      const unsigned short* kp = base + (size_t)(s0 + (j & 3) * 16 + l16) * 3072 + quad * 8;
      bf16x8 bk0 = *(const bf16x8*)(kp);
      bf16x8 bk1 = *(const bf16x8*)(kp + 32);
      f32x4 z = {};
      z = __builtin_amdgcn_mfma_f32_16x16x32_bf16(aq0, bk0, z, 0, 0, 0);
      z = __builtin_amdgcn_mfma_f32_16x16x32_bf16(aq1, bk1, z, 0, 0, 0);
      s[j] = z;
    }
#pragma unroll
    for (int r = 0; r < 4; ++r) {
      float mx = NEGINF;
#pragma unroll
      for (int j = 0; j < 8; ++j) {
        const int kl = (j & 3) * 16 + l16;
        unsigned long long mword = (j < 4) ? swv[r] : hwv[r];
        bool ok = (((mword >> kl) & 1ull) & ((dwv[r] >> kl) & 1ull)) != 0;
        float sv = ok ? s[j][r] * 0.125f : NEGINF;
        s[j][r] = sv;
        mx = fmaxf(mx, sv);
      }
#pragma unroll
      for (int o2 = 8; o2; o2 >>= 1) mx = fmaxf(mx, __shfl_xor(mx, o2));
      const float mn = fmaxf(m_st[r], mx);
      const bool dead = (mn == NEGINF);
      const float alpha = dead ? 1.f : __expf(m_st[r] - mn);
      float rs = 0.f;
#pragma unroll
      for (int j = 0; j < 8; ++j) {
        float p = dead ? 0.f : __expf(s[j][r] - mn);
        s[j][r] = p;
        rs += p;
      }
#pragma unroll
      for (int o2 = 8; o2; o2 >>= 1) rs += __shfl_xor(rs, o2);
      m_st[r] = mn;
      l_st[r] = l_st[r] * alpha + rs;
#pragma unroll
      for (int jd = 0; jd < 4; ++jd) o[jd][r] *= alpha;
#pragma unroll
      for (int j = 0; j < 8; ++j)
        Ps[wv][(quad * 4 + r) * LDV + j * 16 + l16] = f2b(s[j][r]);
    }
    bf16x8 ap[4];
#pragma unroll
    for (int kk = 0; kk < 4; ++kk)
      ap[kk] = *(const bf16x8*)(const void*)&Ps[wv][l16 * LDV + kk * 32 + quad * 8];
#pragma unroll
    for (int jd = 0; jd < 4; ++jd) {
#pragma unroll
      for (int kk = 0; kk < 4; ++kk) {
        bf16x8 bv = *(const bf16x8*)(const void*)&Vt[(jd * 16 + l16) * LDV + kk * 32 + quad * 8];
        o[jd] = __builtin_amdgcn_mfma_f32_16x16x32_bf16(ap[kk], bv, o[jd], 0, 0, 0);
      }
    }
  }
#pragma unroll
  for (int r = 0; r < 4; ++r) {
    const float inv = (l_st[r] > 0.f) ? 1.f / l_st[r] : 0.f;
#pragma unroll
    for (int jd = 0; jd < 4; ++jd)
      y[(size_t)(2048 + rowbase + quad * 4 + r) * 1024 + h * 64 + jd * 16 + l16] = f2b(o[jd][r] * inv);
  }
}

// ---------------------------------------------------------------------------
extern "C" void kernel_launch(void* const* d_in, const int* in_sizes, int n_in,
                              void* d_out, int out_size, void* d_ws, size_t ws_size,
                              hipStream_t stream) {
  const void* xs = d_in[0];
  const void* xh = d_in[1];
  const void* cc = d_in[2];
  const void* mstar = d_in[3];
  const void* mhat = d_in[4];
  const void* mdep = d_in[5];
  const void* ng = d_in[6];
  const void* nb = d_in[7];
  const void* Wq = d_in[8];
  const void* bq = d_in[9];
  const void* Wkv = d_in[10];
  const void* bkv = d_in[11];
  const void* Wco = d_in[12];
  const void* bco = d_in[13];
  const void* Wada = d_in[14];
  const void* bada = d_in[15];
  const void* Wqkv = d_in[16];
  const void* bqkv = d_in[17];
  const void* Wo = d_in[18];
  const void* bo = d_in[19];
  const void* W1 = d_in[20];
  const void* b1 = d_in[21];
  const void* W2 = d_in[22];
  const void* b2 = d_in[23];
  (void)in_sizes; (void)n_in; (void)out_size; (void)ws_size;

  char* ws = (char*)d_ws;
  size_t off = 0;
  auto alloc = [&](size_t bytes) -> char* {
    char* p = ws + off;
    off += (bytes + 255) & ~(size_t)255;
    return p;
  };
  int* flags = (int*)alloc(256);
  unsigned short* ngb = (unsigned short*)alloc(1024 * 2);
  unsigned short* nbb = (unsigned short*)alloc(1024 * 2);
  unsigned short* bqb = (unsigned short*)alloc(1024 * 2);
  unsigned short* bkvb = (unsigned short*)alloc(2048 * 2);
  unsigned short* bcob = (unsigned short*)alloc(1024 * 2);
  unsigned short* badab = (unsigned short*)alloc(6144 * 2);
  unsigned short* bqkvb = (unsigned short*)alloc(3072 * 2);
  unsigned short* bob = (unsigned short*)alloc(1024 * 2);
  unsigned short* b1b = (unsigned short*)alloc(4096 * 2);
  unsigned short* b2b = (unsigned short*)alloc(1024 * 2);
  unsigned short* WqT = (unsigned short*)alloc(1048576ull * 2);
  unsigned short* WkvT = (unsigned short*)alloc(2097152ull * 2);
  unsigned short* WcoT = (unsigned short*)alloc(1048576ull * 2);
  unsigned short* WadaT = (unsigned short*)alloc(6291456ull * 2);
  unsigned short* WqkvT = (unsigned short*)alloc(3145728ull * 2);
  unsigned short* WoT = (unsigned short*)alloc(1048576ull * 2);
  unsigned short* W1T = (unsigned short*)alloc(4194304ull * 2);
  unsigned short* W2T = (unsigned short*)alloc(4194304ull * 2);
  unsigned short* xsb = (unsigned short*)alloc(2097152ull * 2);
  unsigned short* xhb = (unsigned short*)alloc(2097152ull * 2);
  unsigned short* xn = (unsigned short*)alloc(4194304ull * 2);
  unsigned short* qb = (unsigned short*)alloc(4194304ull * 2);
  unsigned short* kvb = (unsigned short*)alloc(1048576ull * 2);
  unsigned short* gada = (unsigned short*)alloc(25165824ull * 2);
  unsigned short* msb = (unsigned short*)alloc(4194304ull * 2);
  unsigned short* qkvb = (unsigned short*)alloc(12582912ull * 2);
  float* x1 = (float*)alloc(4194304ull * 4);
  unsigned short* hid = (unsigned short*)alloc(16777216ull * 2);
  unsigned long long* sbits = (unsigned long long*)alloc(2048ull * 16 * 8);
  unsigned long long* hbits = (unsigned long long*)alloc(2048ull * 16 * 8);
  unsigned long long* dbits = (unsigned long long*)alloc(2048ull * 16 * 8);

  unsigned short* wstage = gada;
  unsigned short* ccb = hid;
  unsigned short* lnx = hid + 1048576;
  unsigned short* yca = xn;
  unsigned short* silub = qb;
  unsigned short* yat = msb;

  dim3 blk(256);
  detect_flags<<<1, blk, 0, stream>>>((const unsigned int*)xs, (const unsigned int*)mdep, flags);

  cvt_bf16<<<2048, blk, 0, stream>>>(xs, xsb, 2097152, flags);
  cvt_bf16<<<2048, blk, 0, stream>>>(xh, xhb, 2097152, flags);
  cvt_bf16<<<512, blk, 0, stream>>>(cc, ccb, 524288, flags);
  cvt_bf16<<<1, blk, 0, stream>>>(ng, ngb, 1024, flags);
  cvt_bf16<<<1, blk, 0, stream>>>(nb, nbb, 1024, flags);
  cvt_bf16<<<1, blk, 0, stream>>>(bq, bqb, 1024, flags);
  cvt_bf16<<<2, blk, 0, stream>>>(bkv, bkvb, 2048, flags);
  cvt_bf16<<<1, blk, 0, stream>>>(bco, bcob, 1024, flags);
  cvt_bf16<<<6, blk, 0, stream>>>(bada, badab, 6144, flags);
  cvt_bf16<<<3, blk, 0, stream>>>(bqkv, bqkvb, 3072, flags);
  cvt_bf16<<<1, blk, 0, stream>>>(bo, bob, 1024, flags);
  cvt_bf16<<<4, blk, 0, stream>>>(b1, b1b, 4096, flags);
  cvt_bf16<<<1, blk, 0, stream>>>(b2, b2b, 1024, flags);

  cvt_bf16<<<1024, blk, 0, stream>>>(Wq, wstage, 1048576, flags);
  transpose_bf16<<<dim3(32, 32), blk, 0, stream>>>(wstage, WqT, 1024, 1024);
  cvt_bf16<<<2048, blk, 0, stream>>>(Wkv, wstage, 2097152, flags);
  transpose_bf16<<<dim3(32, 64), blk, 0, stream>>>(wstage, WkvT, 1024, 2048);
  cvt_bf16<<<1024, blk, 0, stream>>>(Wco, wstage, 1048576, flags);
  transpose_bf16<<<dim3(32, 32), blk, 0, stream>>>(wstage, WcoT, 1024, 1024);
  cvt_bf16<<<6144, blk, 0, stream>>>(Wada, wstage, 6291456, flags);
  transpose_bf16<<<dim3(32, 192), blk, 0, stream>>>(wstage, WadaT, 1024, 6144);
  cvt_bf16<<<3072, blk, 0, stream>>>(Wqkv, wstage, 3145728, flags);
  transpose_bf16<<<dim3(32, 96), blk, 0, stream>>>(wstage, WqkvT, 1024, 3072);
  cvt_bf16<<<1024, blk, 0, stream>>>(Wo, wstage, 1048576, flags);
  transpose_bf16<<<dim3(32, 32), blk, 0, stream>>>(wstage, WoT, 1024, 1024);
  cvt_bf16<<<4096, blk, 0, stream>>>(W1, wstage, 4194304, flags);
  transpose_bf16<<<dim3(32, 128), blk, 0, stream>>>(wstage, W1T, 1024, 4096);
  cvt_bf16<<<4096, blk, 0, stream>>>(W2, wstage, 4194304, flags);
  transpose_bf16<<<dim3(128, 32), blk, 0, stream>>>(wstage, W2T, 4096, 1024);

  pack_mask<<<512, blk, 0, stream>>>(mstar, sbits, flags);
  pack_mask<<<512, blk, 0, stream>>>(mhat, hbits, flags);
  pack_mask<<<512, blk, 0, stream>>>(mdep, dbits, flags);

  ln_affine<<<4096, blk, 0, stream>>>(xsb, xhb, ngb, nbb, lnx, xn);
  gemm_bt<EPI_BF16><<<dim3(32, 8), blk, 0, stream>>>(xn, WqT, bqb, qb, 4096, 1024, 1024, nullptr, nullptr, nullptr, nullptr);
  gemm_bt<EPI_BF16><<<dim3(4, 16), blk, 0, stream>>>(ccb, WkvT, bkvb, kvb, 512, 2048, 1024, nullptr, nullptr, nullptr, nullptr);
  cross_attn_mfma<<<1024, blk, 0, stream>>>(qb, kvb, yca);
  gemm_bt<EPI_SILU><<<dim3(32, 8), blk, 0, stream>>>(yca, WcoT, bcob, silub, 4096, 1024, 1024, nullptr, nullptr, nullptr, nullptr);
  gemm_bt<EPI_BF16><<<dim3(32, 48), blk, 0, stream>>>(silub, WadaT, badab, gada, 4096, 6144, 1024, nullptr, nullptr, nullptr, nullptr);
  mod_ms<<<4096, blk, 0, stream>>>(lnx, gada, msb);
  gemm_bt<EPI_BF16><<<dim3(32, 24), blk, 0, stream>>>(msb, WqkvT, bqkvb, qkvb, 4096, 3072, 1024, nullptr, nullptr, nullptr, nullptr);
  star_attn_mfma<<<512, blk, 0, stream>>>(qkvb, dbits, yat);
  hat_attn_mfma<<<512, blk, 0, stream>>>(qkvb, sbits, hbits, dbits, yat);
  gemm_bt<EPI_GATE_XRES><<<dim3(32, 8), blk, 0, stream>>>(yat, WoT, bob, x1, 4096, 1024, 1024, gada + 2048, xsb, xhb, nullptr);
  ln_mod<<<4096, blk, 0, stream>>>(x1, gada, msb);
  gemm_bt<EPI_GELU><<<dim3(32, 32), blk, 0, stream>>>(msb, W1T, b1b, hid, 4096, 4096, 1024, nullptr, nullptr, nullptr, nullptr);
  gemm_bt<EPI_GATE_OUT><<<dim3(32, 8), blk, 0, stream>>>(hid, W2T, b2b, d_out, 4096, 1024, 4096, gada + 5120, x1, nullptr, flags);
}